// Round 8
// baseline (398.488 us; speedup 1.0000x reference)
//
#include <hip/hip_runtime.h>
#include <hip/hip_bf16.h>
#include <stdint.h>

#define N_DIM 2048
#define BATCH_SZ 8192

typedef __bf16 bf16;
typedef __bf16 bf16x4 __attribute__((ext_vector_type(4)));
typedef __bf16 bf16x8 __attribute__((ext_vector_type(8)));
typedef float f32x4 __attribute__((ext_vector_type(4)));

// Async global->LDS, 16B per lane. LDS dest is wave-uniform base + lane*16.
__device__ __forceinline__ void gld16(const bf16* g, bf16* l) {
  __builtin_amdgcn_global_load_lds(
      (const __attribute__((address_space(1))) void*)g,
      (__attribute__((address_space(3))) void*)l, 16, 0, 0);
}

// ---------------------------------------------------------------------------
// Tiled unfold (proven R7): coalesced reads/writes via padded-LDS transpose.
__global__ __launch_bounds__(256) void unfold_t(const float* __restrict__ Sflat,
                                                bf16* __restrict__ Wb,
                                                bf16* __restrict__ Wtb) {
  const int bi = blockIdx.y;   // tile row
  const int bj = blockIdx.x;   // tile col
  if (bi > bj) return;
  __shared__ float U[64][65];
  const int t  = threadIdx.x;
  const int c  = t & 63;
  const int r0 = t >> 6;       // 0..3

#pragma unroll
  for (int k = 0; k < 16; ++k) {
    const int r = k * 4 + r0;
    const int i = bi * 64 + r;
    const int j = bj * 64 + c;
    float v = 0.0f;
    if (i < j) {
      const int fi = i * (N_DIM - 1) - ((i * (i - 1)) >> 1) + (j - i - 1);
      v = Sflat[fi];
    }
    U[r][c] = v;
  }
  __syncthreads();

  if (bi == bj) {
#pragma unroll
    for (int k = 0; k < 16; ++k) {
      const int r = k * 4 + r0;
      const float s = U[r][c] - U[c][r];
      const size_t idx = (size_t)(bi * 64 + r) * N_DIM + bj * 64 + c;
      Wb[idx]  = (bf16)(-s);
      Wtb[idx] = (bf16)( s);
    }
  } else {
#pragma unroll
    for (int k = 0; k < 16; ++k) {
      const int r = k * 4 + r0;
      const float u = U[r][c];
      const size_t idx = (size_t)(bi * 64 + r) * N_DIM + bj * 64 + c;
      Wb[idx]  = (bf16)(-u);
      Wtb[idx] = (bf16)( u);
      const float um = U[c][r];
      const size_t idm = (size_t)(bj * 64 + r) * N_DIM + bi * 64 + c;
      Wb[idm]  = (bf16)( um);
      Wtb[idm] = (bf16)(-um);
    }
  }
}

// fp32 -> bf16 elementwise (vectorized x4)
__global__ void cast_kernel(const float* __restrict__ in, bf16* __restrict__ out) {
  int t = blockIdx.x * blockDim.x + threadIdx.x;
  float4 v = ((const float4*)in)[t];
  bf16x4 o;
  o.x = (bf16)v.x; o.y = (bf16)v.y; o.z = (bf16)v.z; o.w = (bf16)v.w;
  ((bf16x4*)out)[t] = o;
}

// ---------------------------------------------------------------------------
// One weight-GEMM phase: C(128x128 tile) = A @ Bt^T over K=2048, bf16 in,
// fp32 acc. 512 threads = 8 waves (2M x 4N), per-wave 64x32 output.
// BK=128 periods (4 x 32-col sub-buffers), LDS ring-2 (128 KiB total):
// at the top of period t, stage period t+1 into the half consumed in t-1
// (safe: the t-1 boundary barrier has passed). ONE barrier + one fully-aged
// vmcnt(0) per 128 K-depth -> 16 barrier-periods/phase vs gemm_w's 32-64
// (theory: fixed ~1700 cy/barrier-period overhead dominated all prior
// weight-GEMM variants).
// MODE 1: O1 = bf16(acc) [W2];  O2 = bf16(I/2 - W/6 + acc/24) [B^T operand]
// MODE 2: O1 = bf16(acc + I + W)                          (Q^T)
template <int MODE>
__device__ __forceinline__ void gemm128_phase(
    const bf16* __restrict__ A, const bf16* __restrict__ Bt,
    bf16* __restrict__ O1, bf16* __restrict__ O2,
    const bf16* __restrict__ Wb, bf16* As, bf16* Bs, int m0, int n0) {
  constexpr int K  = N_DIM;
  constexpr int NP = K >> 7;     // 16 periods of BK=128
  const int tid  = threadIdx.x;
  const int lane = tid & 63;
  const int wave = tid >> 6;     // 0..7
  const int wr   = wave >> 2;    // 0..1  M-half (64 rows)
  const int wc   = wave & 3;     // 0..3  N-quarter (32 cols)
  const int quad = lane >> 4;
  const int l16  = lane & 15;

  // Staging swizzle (verified conflict-free R0-R7):
  // LDS[row][c] = G[row][c ^ ((row>>1)&3)] per 8-elem segment.
  const int srow  = lane >> 2;
  const int sslot = (lane & 3) ^ ((lane >> 3) & 3);
  const bf16* gA = A  + (size_t)(m0 + wave * 16 + srow) * K + sslot * 8;
  const bf16* gB = Bt + (size_t)(n0 + wave * 16 + srow) * K + sslot * 8;
  bf16* lA = As + wave * 512;    // + sub*4096
  bf16* lB = Bs + wave * 512;

  // Prologue: stage period 0 -> half 0 (8 loads/thread); drain; barrier.
#pragma unroll
  for (int k = 0; k < 4; ++k) {
    gld16(gA + k * 32, lA + k * 4096);
    gld16(gB + k * 32, lB + k * 4096);
  }
  asm volatile("s_waitcnt vmcnt(0)" ::: "memory");
  __builtin_amdgcn_sched_barrier(0);
  __builtin_amdgcn_s_barrier();
  __builtin_amdgcn_sched_barrier(0);

  f32x4 acc[4][2] = {};
  const int rswz = (quad ^ ((l16 >> 1) & 3)) * 8;
  const int arow = wr * 64 + l16;
  const int brow = wc * 32 + l16;

#pragma unroll 1
  for (int t = 0; t < NP; ++t) {
    // Stage period t+1 into the other half (fully consumed in period t-1;
    // its boundary barrier has passed -> cross-wave safe).
    if (t + 1 < NP) {
      const int h = ((t + 1) & 1) * 4;
      const size_t ko = (size_t)(t + 1) * 128;
#pragma unroll
      for (int k = 0; k < 4; ++k) {
        gld16(gA + ko + k * 32, lA + (h + k) * 4096);
        gld16(gB + ko + k * 32, lB + (h + k) * 4096);
      }
    }
    __builtin_amdgcn_sched_barrier(0);
    const int base = (t & 1) * 4;
#pragma unroll
    for (int kk = 0; kk < 4; ++kk) {
      const bf16* ab = As + (base + kk) * 4096;
      const bf16* bb = Bs + (base + kk) * 4096;
      bf16x8 af[4], bfr[2];
#pragma unroll
      for (int mi = 0; mi < 4; ++mi)
        af[mi] = *(const bf16x8*)&ab[(arow + mi * 16) * 32 + rswz];
#pragma unroll
      for (int ni = 0; ni < 2; ++ni)
        bfr[ni] = *(const bf16x8*)&bb[(brow + ni * 16) * 32 + rswz];
      __builtin_amdgcn_s_setprio(1);
#pragma unroll
      for (int mi = 0; mi < 4; ++mi)
#pragma unroll
        for (int ni = 0; ni < 2; ++ni)
          acc[mi][ni] = __builtin_amdgcn_mfma_f32_16x16x32_bf16(
              af[mi], bfr[ni], acc[mi][ni], 0, 0, 0);
      __builtin_amdgcn_s_setprio(0);
    }
    // Boundary: t+1's loads have been in flight for a full period
    // (~>1400 cy >> load latency), so this drain is ~free.
    if (t + 1 < NP) {
      asm volatile("s_waitcnt vmcnt(0)" ::: "memory");
      __builtin_amdgcn_sched_barrier(0);
      __builtin_amdgcn_s_barrier();
      __builtin_amdgcn_sched_barrier(0);
    }
  }

  // Epilogue. C/D layout: col = lane&15, row = quad*4 + reg.
#pragma unroll
  for (int mi = 0; mi < 4; ++mi) {
    const int r0 = m0 + wr * 64 + mi * 16 + quad * 4;
#pragma unroll
    for (int ni = 0; ni < 2; ++ni) {
      const int col = n0 + wc * 32 + ni * 16 + l16;
#pragma unroll
      for (int r = 0; r < 4; ++r) {
        const int row = r0 + r;
        const size_t idx = (size_t)row * N_DIM + col;
        const float v = acc[mi][ni][r];
        if (MODE == 1) {
          // v = W2[row][col]. B = I/2 + W/6 + W2/24 ->
          // B^T = I/2 - W/6 + W2/24  (W antisymmetric, W2 symmetric).
          O1[idx] = (bf16)v;
          const float w = (float)Wb[idx];
          const float d = (row == col) ? 1.0f : 0.0f;
          O2[idx] = (bf16)(0.5f * d - (1.0f / 6.0f) * w + (1.0f / 24.0f) * v);
        } else {  // MODE 2: Q^T = acc + I + W
          const float w = (float)Wb[idx];
          const float d = (row == col) ? 1.0f : 0.0f;
          O1[idx] = (bf16)(v + d + w);
        }
      }
    }
  }
}

// Fused weight pipeline: phase 1 (W2 = W @ W, emit W2b + Btm) ->
// device-scope arrival barrier (all 256 blocks co-resident: 128 KiB LDS ->
// 1 block/CU, grid == CU count) -> phase 2 (Qtb = I + W + W2 @ B).
__global__ __launch_bounds__(512, 1) void wfused(
    const bf16* __restrict__ Wb, const bf16* __restrict__ Wtb,
    bf16* __restrict__ W2b, bf16* __restrict__ Btm,
    bf16* __restrict__ Qtb, unsigned* __restrict__ cnt) {
  __shared__ __align__(16) bf16 As[8 * 128 * 32];   // 64 KB (2 halves x 4 subs)
  __shared__ __align__(16) bf16 Bs[8 * 128 * 32];   // 64 KB

  // Bijective XCD swizzle (256 blocks, 16x16 tile grid).
  const int linear = blockIdx.x;
  const int wg = (linear & 7) * 32 + (linear >> 3);
  const int m0 = (wg >> 4) * 128;
  const int n0 = (wg & 15) * 128;

  gemm128_phase<1>(Wb, Wtb, W2b, Btm, Wb, As, Bs, m0, n0);

  // Grid-wide barrier: release phase-1 stores, arrive, spin, acquire.
  __threadfence();
  __syncthreads();
  if (threadIdx.x == 0) {
    __hip_atomic_fetch_add(cnt, 1u, __ATOMIC_ACQ_REL, __HIP_MEMORY_SCOPE_AGENT);
    while (__hip_atomic_load(cnt, __ATOMIC_ACQUIRE, __HIP_MEMORY_SCOPE_AGENT) <
           256u)
      __builtin_amdgcn_s_sleep(8);
  }
  __syncthreads();
  __threadfence();

  gemm128_phase<2>(W2b, Btm, Qtb, nullptr, Wb, As, Bs, m0, n0);
}

// ---------------------------------------------------------------------------
// G3 kernel (frozen at round-1 version: best measured, 77 us, ~890 TF).
__global__ __launch_bounds__(512, 2) void gemm256(
    const bf16* __restrict__ A, const bf16* __restrict__ Bt,
    float* __restrict__ Cf, int M, int N, int K) {
  __shared__ __align__(16) bf16 As[4 * 256 * 32];   // 64 KB
  __shared__ __align__(16) bf16 Bs[4 * 256 * 32];   // 64 KB

  const int tid  = threadIdx.x;
  const int lane = tid & 63;
  const int wave = tid >> 6;     // 0..7
  const int wr   = wave >> 2;    // 0..1  M-half
  const int wc   = wave & 3;     // 0..3  N-quarter
  const int quad = lane >> 4;
  const int l16  = lane & 15;

  const int nwg    = gridDim.x * gridDim.y;
  const int linear = blockIdx.y * gridDim.x + blockIdx.x;
  const int wg = (linear & 7) * (nwg >> 3) + (linear >> 3);
  const int bx = wg & 7;         // gridDim.x == 8 (N == 2048)
  const int by = wg >> 3;
  const int m0 = by * 256;
  const int n0 = bx * 256;

  const int srow  = lane >> 2;
  const int sslot = (lane & 3) ^ ((lane >> 3) & 3);
  const bf16* pA1 = A  + (size_t)(m0 + wave * 16 + srow) * K + sslot * 8;
  const bf16* pA2 = pA1 + (size_t)128 * K;
  const bf16* pB1 = Bt + (size_t)(n0 + wave * 16 + srow) * K + sslot * 8;
  const bf16* pB2 = pB1 + (size_t)128 * K;
  bf16* lA1 = As + wave * 512;          // + buf*8192
  bf16* lA2 = As + wave * 512 + 4096;
  bf16* lB1 = Bs + wave * 512;
  bf16* lB2 = Bs + wave * 512 + 4096;

  const int NT = K >> 5;   // K-tiles of 32

#pragma unroll
  for (int tt = 0; tt < 3; ++tt) {
    gld16(pA1 + tt * 32, lA1 + tt * 8192);
    gld16(pA2 + tt * 32, lA2 + tt * 8192);
    gld16(pB1 + tt * 32, lB1 + tt * 8192);
    gld16(pB2 + tt * 32, lB2 + tt * 8192);
  }
  asm volatile("s_waitcnt vmcnt(8)" ::: "memory");
  __builtin_amdgcn_s_barrier();
  __builtin_amdgcn_sched_barrier(0);

  f32x4 acc[8][4] = {};
  const int rswz = (quad ^ ((l16 >> 1) & 3)) * 8;  // reader swizzle (elems)
  const int arow = wr * 128 + l16;
  const int brow = wc * 64 + l16;

  size_t kpre = 96;   // element k-offset of tile t+3 at t=0

#pragma unroll 1
  for (int t4 = 0; t4 < NT; t4 += 4) {
#pragma unroll
    for (int u = 0; u < 4; ++u) {
      const int t = t4 + u;
      if (t + 3 < NT) {
        const int b = (u + 3) & 3;
        const size_t ko = kpre + (size_t)u * 32;
        gld16(pA1 + ko, lA1 + b * 8192);
        gld16(pA2 + ko, lA2 + b * 8192);
        gld16(pB1 + ko, lB1 + b * 8192);
        gld16(pB2 + ko, lB2 + b * 8192);
      }
      const bf16* ab = As + u * 8192;
      const bf16* bb = Bs + u * 8192;
      bf16x8 af[8], bfr[4];
#pragma unroll
      for (int mi = 0; mi < 8; ++mi)
        af[mi] = *(const bf16x8*)&ab[(arow + mi * 16) * 32 + rswz];
#pragma unroll
      for (int ni = 0; ni < 4; ++ni)
        bfr[ni] = *(const bf16x8*)&bb[(brow + ni * 16) * 32 + rswz];
      __builtin_amdgcn_s_setprio(1);
#pragma unroll
      for (int mi = 0; mi < 8; ++mi)
#pragma unroll
        for (int ni = 0; ni < 4; ++ni)
          acc[mi][ni] = __builtin_amdgcn_mfma_f32_16x16x32_bf16(
              af[mi], bfr[ni], acc[mi][ni], 0, 0, 0);
      __builtin_amdgcn_s_setprio(0);
      if (t < NT - 1) {
        if (t < NT - 3)
          asm volatile("s_waitcnt vmcnt(8)" ::: "memory");
        else if (t == NT - 3)
          asm volatile("s_waitcnt vmcnt(4)" ::: "memory");
        else
          asm volatile("s_waitcnt vmcnt(0)" ::: "memory");
        __builtin_amdgcn_sched_barrier(0);
        __builtin_amdgcn_s_barrier();
        __builtin_amdgcn_sched_barrier(0);
      }
    }
    kpre += 128;
  }

#pragma unroll
  for (int mi = 0; mi < 8; ++mi) {
    const int r0 = m0 + wr * 128 + mi * 16 + quad * 4;
#pragma unroll
    for (int ni = 0; ni < 4; ++ni) {
      const int col = n0 + wc * 64 + ni * 16 + l16;
#pragma unroll
      for (int r = 0; r < 4; ++r)
        Cf[(size_t)(r0 + r) * N + col] = acc[mi][ni][r];
    }
  }
}

extern "C" void kernel_launch(void* const* d_in, const int* in_sizes, int n_in,
                              void* d_out, int out_size, void* d_ws, size_t ws_size,
                              hipStream_t stream) {
  const float* X     = (const float*)d_in[0];
  const float* Sflat = (const float*)d_in[1];
  float* out = (float*)d_out;
  char* ws = (char*)d_ws;

  // Workspace (72 MB total):
  bf16* Xb   = (bf16*)(ws);                 // 32 MB  bf16(X)
  bf16* Wb   = (bf16*)(ws + (32u << 20));   //  8 MB  bf16(W),   W = -S
  bf16* Wtb  = (bf16*)(ws + (40u << 20));   //  8 MB  bf16(W^T)
  bf16* W2b  = (bf16*)(ws + (48u << 20));   //  8 MB  bf16(W^2)
  bf16* Btm  = (bf16*)(ws + (56u << 20));   //  8 MB  bf16(B^T) operand for G2
  bf16* Qtb  = (bf16*)(ws + (64u << 20));   //  8 MB  bf16(Q^T)

  // Barrier counter lives at the head of d_out (dead until G3 overwrites it);
  // reset every graph replay.
  hipMemsetAsync(out, 0, 64, stream);

  unfold_t<<<dim3(32, 32), 256, 0, stream>>>(Sflat, Wb, Wtb);
  cast_kernel<<<(BATCH_SZ * N_DIM / 4) / 256, 256, 0, stream>>>(X, Xb);

  // Fused weight pipeline: G1 -> grid barrier -> G2 in one dispatch.
  // 256 blocks (1/CU, all co-resident), 128x128 tiles, BK=128 ring-2.
  wfused<<<256, 512, 0, stream>>>(Wb, Wtb, W2b, Btm, Qtb, (unsigned*)out);

  // G3: out = X @ Q (Bt = Q^T row-major). Frozen round-1 kernel.
  gemm256<<<dim3(N_DIM / 256, BATCH_SZ / 256), 512, 0, stream>>>(
      Xb, Qtb, out, BATCH_SZ, N_DIM, N_DIM);
}